// Round 1
// baseline (266.021 us; speedup 1.0000x reference)
//
#include <hip/hip_runtime.h>

#define K    32
#define TPB  256
#define EPT  8           // elements per thread
#define NB   1024        // main-kernel grid (N / (TPB*EPT))
#define NTOT (32*64*1024)

__device__ __forceinline__ float wave_reduce_sum(float v) {
#pragma unroll
  for (int m = 1; m < 64; m <<= 1) v += __shfl_xor(v, m, 64);
  return v;
}

__global__ __launch_bounds__(TPB, 4)
void ssq_main(const float* __restrict__ x, const float* __restrict__ bins,
              float* __restrict__ out, float* __restrict__ partials) {
  const int tid   = threadIdx.x;
  const int gbase = (blockIdx.x * TPB + tid) * EPT;

  // bins are wave-uniform loads -> compiler should keep them in SGPRs
  float binv[K];
#pragma unroll
  for (int k = 0; k < K; ++k) binv[k] = bins[k];

  float sAcc[K];
#pragma unroll
  for (int k = 0; k < K; ++k) sAcc[k] = 0.f;
  float q0 = 0.f, q1 = 0.f, q2 = 0.f, q3 = 0.f;   // quant partials (break dep chain)

  const float C = -14.426950408889634f;  // ALPHA * log2(e)

  float4 xa = *(const float4*)(x + gbase);
  float4 xb = *(const float4*)(x + gbase + 4);
  float xs[8] = {xa.x, xa.y, xa.z, xa.w, xb.x, xb.y, xb.z, xb.w};
  float res[8];

#pragma unroll
  for (int e = 0; e < EPT; ++e) {
    const float xv = xs[e];
    float l[K];
    float s0 = 0.f, s1 = 0.f, s2 = 0.f, s3 = 0.f;
#pragma unroll
    for (int k = 0; k < K; k += 4) {
      float t0 = __builtin_amdgcn_exp2f(C * fabsf(xv - binv[k + 0]));
      float t1 = __builtin_amdgcn_exp2f(C * fabsf(xv - binv[k + 1]));
      float t2 = __builtin_amdgcn_exp2f(C * fabsf(xv - binv[k + 2]));
      float t3 = __builtin_amdgcn_exp2f(C * fabsf(xv - binv[k + 3]));
      l[k + 0] = t0; l[k + 1] = t1; l[k + 2] = t2; l[k + 3] = t3;
      s0 += t0; s1 += t1; s2 += t2; s3 += t3;
    }
    const float inv = __builtin_amdgcn_rcpf((s0 + s1) + (s2 + s3));
    float b0 = 0.f, b1 = 0.f, b2 = 0.f, b3 = 0.f;
#pragma unroll
    for (int k = 0; k < K; k += 4) {
      float a0 = fmaf(l[k + 0], inv, 1e-10f);
      float a1 = fmaf(l[k + 1], inv, 1e-10f);
      float a2 = fmaf(l[k + 2], inv, 1e-10f);
      float a3 = fmaf(l[k + 3], inv, 1e-10f);
      sAcc[k + 0] += a0; sAcc[k + 1] += a1;
      sAcc[k + 2] += a2; sAcc[k + 3] += a3;
      q0 += __builtin_amdgcn_sqrtf(a0);
      q1 += __builtin_amdgcn_sqrtf(a1);
      q2 += __builtin_amdgcn_sqrtf(a2);
      q3 += __builtin_amdgcn_sqrtf(a3);
      b0 = fmaf(a0, binv[k + 0], b0);
      b1 = fmaf(a1, binv[k + 1], b1);
      b2 = fmaf(a2, binv[k + 2], b2);
      b3 = fmaf(a3, binv[k + 3], b3);
    }
    res[e] = (b0 + b1) + (b2 + b3);
  }

  float4 ra = {res[0], res[1], res[2], res[3]};
  float4 rb = {res[4], res[5], res[6], res[7]};
  *(float4*)(out + gbase)     = ra;
  *(float4*)(out + gbase + 4) = rb;

  // block reduction: wave shuffle -> LDS -> one write per counter
  __shared__ float red[4][K + 1];
  const int lane = tid & 63, wv = tid >> 6;
#pragma unroll
  for (int k = 0; k < K; ++k) {
    float v = wave_reduce_sum(sAcc[k]);
    if (lane == 0) red[wv][k] = v;
  }
  {
    float v = wave_reduce_sum(((q0 + q1) + (q2 + q3)));
    if (lane == 0) red[wv][K] = v;
  }
  __syncthreads();
  if (tid < K + 1) {
    float v = red[0][tid] + red[1][tid] + red[2][tid] + red[3][tid];
    partials[tid * NB + blockIdx.x] = v;   // each slot written exactly once
  }
}

__global__ __launch_bounds__(512)
void ssq_final(const float* __restrict__ partials, float* __restrict__ out) {
  __shared__ float red[K + 1][17];
  const int t = threadIdx.x;
  const int k = t >> 4, g = t & 15;       // 32 k's x 16 groups of 64 blocks
  float s = 0.f;
  for (int b = g * 64; b < g * 64 + 64; ++b) s += partials[k * NB + b];
  red[k][g] = s;
  if (t < 16) {
    float s2 = 0.f;
    for (int b = t * 64; b < t * 64 + 64; ++b) s2 += partials[K * NB + b];
    red[K][t] = s2;
  }
  __syncthreads();
  if (t == 0) {
    const float invN = 1.0f / (float)NTOT;
    float quant = 0.f;
    for (int g2 = 0; g2 < 16; ++g2) quant += red[K][g2];
    quant *= invN;
    float ent = 0.f;
    for (int kk = 0; kk < K; ++kk) {
      float S = 0.f;
      for (int g2 = 0; g2 < 16; ++g2) S += red[kk][g2];
      float p = S * invN;
      ent -= p * __logf(p);
    }
    out[NTOT + 0] = ent;     // weighted_code_entropy[0,0]
    out[NTOT + 1] = 0.f;     // TAU
    out[NTOT + 2] = quant;   // weighted_quant_loss[0,0]
    out[NTOT + 3] = 0.f;     // TAU2
  }
}

extern "C" void kernel_launch(void* const* d_in, const int* in_sizes, int n_in,
                              void* d_out, int out_size, void* d_ws, size_t ws_size,
                              hipStream_t stream) {
  const float* x    = (const float*)d_in[0];
  const float* bins = (const float*)d_in[1];
  float* out        = (float*)d_out;
  float* partials   = (float*)d_ws;      // (K+1) * NB floats = 132 KB

  ssq_main<<<NB, TPB, 0, stream>>>(x, bins, out, partials);
  ssq_final<<<1, 512, 0, stream>>>(partials, out);
}

// Round 2
// 115.435 us; speedup vs baseline: 2.3045x; 2.3045x over previous
//
#include <hip/hip_runtime.h>

#define K      32
#define TPB    256
#define NB     1024                 // main-kernel blocks
#define EPT    8                    // elements per thread (grid-stride)
#define NTOT   (32 * 64 * 1024)    // 2,097,152
#define STRIDE (TPB * NB)

__device__ __forceinline__ float wave_reduce_sum(float v) {
#pragma unroll
  for (int m = 1; m < 64; m <<= 1) v += __shfl_xor(v, m, 64);
  return v;
}

// NOTE: no min-waves hint — R0's __launch_bounds__(256,4) capped VGPRs and
// caused catastrophic scratch spill (250MB fetch / 380MB write observed).
__global__ __launch_bounds__(TPB)
void ssq_main(const float* __restrict__ x, const float* __restrict__ bins,
              float* __restrict__ out, float* __restrict__ partials) {
  const int tid  = threadIdx.x;
  const int base = blockIdx.x * TPB + tid;

  // wave-uniform loads -> SGPRs
  float binv[K];
#pragma unroll
  for (int k = 0; k < K; ++k) binv[k] = bins[k];

  // all 8 loads issued up front, coalesced (lane i -> consecutive addresses)
  float xs[EPT];
#pragma unroll
  for (int e = 0; e < EPT; ++e) xs[e] = x[base + e * STRIDE];

  float sAcc[K];
#pragma unroll
  for (int k = 0; k < K; ++k) sAcc[k] = 0.f;
  float q0 = 0.f, q1 = 0.f, q2 = 0.f, q3 = 0.f;

  const float C = -14.426950408889634f;  // ALPHA * log2(e)

#pragma unroll
  for (int e = 0; e < EPT; ++e) {
    const float xv = xs[e];
    float l[K];
    float s0 = 0.f, s1 = 0.f, s2 = 0.f, s3 = 0.f;
#pragma unroll
    for (int k = 0; k < K; k += 4) {
      float t0 = __builtin_amdgcn_exp2f(C * fabsf(xv - binv[k + 0]));
      float t1 = __builtin_amdgcn_exp2f(C * fabsf(xv - binv[k + 1]));
      float t2 = __builtin_amdgcn_exp2f(C * fabsf(xv - binv[k + 2]));
      float t3 = __builtin_amdgcn_exp2f(C * fabsf(xv - binv[k + 3]));
      l[k + 0] = t0; l[k + 1] = t1; l[k + 2] = t2; l[k + 3] = t3;
      s0 += t0; s1 += t1; s2 += t2; s3 += t3;
    }
    const float inv = __builtin_amdgcn_rcpf((s0 + s1) + (s2 + s3));
    float b0 = 0.f, b1 = 0.f, b2 = 0.f, b3 = 0.f;
#pragma unroll
    for (int k = 0; k < K; k += 4) {
      float a0 = fmaf(l[k + 0], inv, 1e-10f);
      float a1 = fmaf(l[k + 1], inv, 1e-10f);
      float a2 = fmaf(l[k + 2], inv, 1e-10f);
      float a3 = fmaf(l[k + 3], inv, 1e-10f);
      sAcc[k + 0] += a0; sAcc[k + 1] += a1;
      sAcc[k + 2] += a2; sAcc[k + 3] += a3;
      q0 += __builtin_amdgcn_sqrtf(a0);
      q1 += __builtin_amdgcn_sqrtf(a1);
      q2 += __builtin_amdgcn_sqrtf(a2);
      q3 += __builtin_amdgcn_sqrtf(a3);
      b0 = fmaf(a0, binv[k + 0], b0);
      b1 = fmaf(a1, binv[k + 1], b1);
      b2 = fmaf(a2, binv[k + 2], b2);
      b3 = fmaf(a3, binv[k + 3], b3);
    }
    out[base + e * STRIDE] = (b0 + b1) + (b2 + b3);
  }

  // block reduction: wave shuffle -> LDS -> one partial per counter per block
  __shared__ float red[4][K + 1];
  const int lane = tid & 63, wv = tid >> 6;
#pragma unroll
  for (int k = 0; k < K; ++k) {
    float v = wave_reduce_sum(sAcc[k]);
    if (lane == 0) red[wv][k] = v;
  }
  {
    float v = wave_reduce_sum((q0 + q1) + (q2 + q3));
    if (lane == 0) red[wv][K] = v;
  }
  __syncthreads();
  if (tid < K + 1) {
    float v = red[0][tid] + red[1][tid] + red[2][tid] + red[3][tid];
    partials[tid * NB + blockIdx.x] = v;   // written exactly once, no init needed
  }
}

// 33 blocks: block c reduces partials[c*NB .. c*NB+NB) -> sums[c]
__global__ __launch_bounds__(TPB)
void ssq_reduce(const float* __restrict__ partials, float* __restrict__ sums) {
  const float* p = partials + blockIdx.x * NB;
  const int tid  = threadIdx.x;
  float s = p[tid] + p[tid + 256] + p[tid + 512] + p[tid + 768];
  s = wave_reduce_sum(s);
  __shared__ float red[4];
  if ((tid & 63) == 0) red[tid >> 6] = s;
  __syncthreads();
  if (tid == 0) sums[blockIdx.x] = red[0] + red[1] + red[2] + red[3];
}

// one wave: entropy over 32 p_k + quant mean + tails
__global__ void ssq_final(const float* __restrict__ sums, float* __restrict__ out) {
  const int lane = threadIdx.x;
  float e = 0.f;
  if (lane < K) {
    float p = sums[lane] * (1.0f / (float)NTOT);
    e = -p * __logf(p);
  }
  e = wave_reduce_sum(e);
  if (lane == 0) {
    out[NTOT + 0] = e;                              // code entropy
    out[NTOT + 1] = 0.f;                            // TAU
    out[NTOT + 2] = sums[K] * (1.0f / (float)NTOT); // quant loss
    out[NTOT + 3] = 0.f;                            // TAU2
  }
}

extern "C" void kernel_launch(void* const* d_in, const int* in_sizes, int n_in,
                              void* d_out, int out_size, void* d_ws, size_t ws_size,
                              hipStream_t stream) {
  const float* x    = (const float*)d_in[0];
  const float* bins = (const float*)d_in[1];
  float* out        = (float*)d_out;
  float* partials   = (float*)d_ws;                 // (K+1)*NB floats = 132 KB
  float* sums       = partials + (K + 1) * NB;      // 33 floats

  ssq_main  <<<NB,     TPB, 0, stream>>>(x, bins, out, partials);
  ssq_reduce<<<K + 1,  TPB, 0, stream>>>(partials, sums);
  ssq_final <<<1,      64,  0, stream>>>(sums, out);
}